// Round 2
// baseline (75.066 us; speedup 1.0000x reference)
//
#include <hip/hip_runtime.h>

// ShiftDisLoss: per-box BEV corner distance loss, weighted global sum / B.
// Inputs: pred_bbox3d [B,N,7] f32, gt_bbox3d [B,N,7] f32, weights [B,N] f32.
// Output: 1 f32 scalar. B=4, N=1e6.
//
// Key algebraic simplification: corners are c±u, c±v with
//   u = (hx*cos - hy*sin, hx*sin + hy*cos), v = (hx*cos + hy*sin, hx*sin - hy*cos)
// Squared-dist-from-origin keys are |c|^2+|u|^2 ± 2c·u / ± 2c·v, so the
// reference's argsort over 4 corners reduces to sign/magnitude selection over
// t0 = c·u, t1 = c·v.  The mid-pair x^2 re-sort reduces to sign(cx*qx).

__device__ __forceinline__ float fast_rcp(float x) {
    return __builtin_amdgcn_rcpf(x);
}

struct SC { float x0, y0, x1, y1, x2, y2, x3, y3; };

__device__ __forceinline__ SC sorted_corners(float cx, float cy,
                                             float dx, float dy, float h) {
    float s = __sinf(h), c = __cosf(h);
    float hx = 0.5f * dx, hy = 0.5f * dy;
    float ux = hx * c - hy * s, uy = hx * s + hy * c;   // corner0 offset
    float vx = hx * c + hy * s, vy = hx * s - hy * c;   // corner1 offset
    float t0 = cx * ux + cy * uy;
    float t1 = cx * vx + cy * vy;
    bool umajor = fabsf(t0) >= fabsf(t1);
    float px = umajor ? ux : vx, py = umajor ? uy : vy;
    float tp = umajor ? t0 : t1;
    float qx = umajor ? vx : ux, qy = umajor ? vy : uy;
    float sp = copysignf(1.0f, tp);
    float sm = copysignf(1.0f, cx * qx);   // mid-pair x^2 ordering
    SC r;
    r.x0 = cx - sp * px; r.y0 = cy - sp * py;   // nearest corner
    r.x1 = cx - sm * qx; r.y1 = cy - sm * qy;   // mid (smaller x^2)
    r.x2 = cx + sm * qx; r.y2 = cy + sm * qy;   // mid (larger x^2)
    r.x3 = cx + sp * px; r.y3 = cy + sp * py;   // farthest corner
    return r;
}

__device__ __forceinline__ float box_loss(float pcx, float pcy, float pdx,
                                          float pdy, float ph,
                                          float gcx, float gcy, float gdx,
                                          float gdy, float gh) {
    SC p = sorted_corners(pcx, pcy, pdx, pdy, ph);
    SC g = sorted_corners(gcx, gcy, gdx, gdy, gh);
    float d1x = g.x1 - g.x0, d1y = g.y1 - g.y0;
    float d2x = g.x2 - g.x0, d2y = g.y2 - g.y0;
    float d3x = g.x3 - g.x0, d3y = g.y3 - g.y0;
    // cross((B-A), (P-A)) — squared, so sign convention is irrelevant
    float n1 = d1x * (p.y1 - g.y0) - d1y * (p.x1 - g.x0);
    float n2 = d2x * (p.y2 - g.y0) - d2y * (p.x2 - g.x0);
    float n3 = d3x * (p.y0 - g.y0) - d3y * (p.x0 - g.x0);
    float gx = g.x1 - g.x2, gy = g.y1 - g.y2;
    float diag = gx * gx + gy * gy;
    float sum = n1 * n1 * fast_rcp(d1x * d1x + d1y * d1y)
              + n2 * n2 * fast_rcp(d2x * d2x + d2y * d2y)
              + n3 * n3 * fast_rcp(d3x * d3x + d3y * d3y);
    return sum * fast_rcp(diag);
}

__global__ __launch_bounds__(256)
void shiftdis_loss_kernel(const float* __restrict__ pred,
                          const float* __restrict__ gt,
                          const float* __restrict__ w,
                          float* __restrict__ out,
                          long long n_boxes, float inv_b) {
    long long gidx = (long long)blockIdx.x * blockDim.x + threadIdx.x;
    long long b0 = gidx * 4;
    float acc = 0.0f;

    if (b0 + 4 <= n_boxes) {
        const float4* p4 = reinterpret_cast<const float4*>(pred + b0 * 7);
        const float4* g4 = reinterpret_cast<const float4*>(gt + b0 * 7);
        float pf[28], gf[28];
#pragma unroll
        for (int i = 0; i < 7; ++i) {
            float4 v = p4[i];
            pf[4 * i + 0] = v.x; pf[4 * i + 1] = v.y;
            pf[4 * i + 2] = v.z; pf[4 * i + 3] = v.w;
            float4 u = g4[i];
            gf[4 * i + 0] = u.x; gf[4 * i + 1] = u.y;
            gf[4 * i + 2] = u.z; gf[4 * i + 3] = u.w;
        }
        float4 wv = *reinterpret_cast<const float4*>(w + b0);
        float wa0 = wv.x, wa1 = wv.y, wa2 = wv.z, wa3 = wv.w;

#pragma unroll
        for (int j = 0; j < 4; ++j) {
            float wj = (j == 0) ? wa0 : (j == 1) ? wa1 : (j == 2) ? wa2 : wa3;
            acc += box_loss(pf[7 * j + 0], pf[7 * j + 1], pf[7 * j + 3],
                            pf[7 * j + 4], pf[7 * j + 6],
                            gf[7 * j + 0], gf[7 * j + 1], gf[7 * j + 3],
                            gf[7 * j + 4], gf[7 * j + 6]) * wj;
        }
    } else if (b0 < n_boxes) {
        for (long long b = b0; b < n_boxes; ++b) {
            const float* p = pred + b * 7;
            const float* q = gt + b * 7;
            acc += box_loss(p[0], p[1], p[3], p[4], p[6],
                            q[0], q[1], q[3], q[4], q[6]) * w[b];
        }
    }

    // wave-64 reduce
#pragma unroll
    for (int off = 32; off > 0; off >>= 1)
        acc += __shfl_down(acc, off, 64);

    __shared__ float wsum[4];
    int lane = threadIdx.x & 63;
    int wid = threadIdx.x >> 6;
    if (lane == 0) wsum[wid] = acc;
    __syncthreads();
    if (threadIdx.x == 0) {
        float bsum = wsum[0] + wsum[1] + wsum[2] + wsum[3];
        atomicAdd(out, bsum * inv_b);
    }
}

extern "C" void kernel_launch(void* const* d_in, const int* in_sizes, int n_in,
                              void* d_out, int out_size, void* d_ws, size_t ws_size,
                              hipStream_t stream) {
    const float* pred = (const float*)d_in[0];
    const float* gt   = (const float*)d_in[1];
    const float* w    = (const float*)d_in[2];
    float* out = (float*)d_out;

    long long n_boxes = (long long)in_sizes[2];   // B*N
    const float inv_b = 0.25f;                    // B = 4

    hipMemsetAsync(d_out, 0, sizeof(float), stream);

    long long groups = (n_boxes + 3) / 4;
    int block = 256;
    long long grid = (groups + block - 1) / block;
    shiftdis_loss_kernel<<<(int)grid, block, 0, stream>>>(pred, gt, w, out,
                                                          n_boxes, inv_b);
}

// Round 3
// 71.942 us; speedup vs baseline: 1.0434x; 1.0434x over previous
//
#include <hip/hip_runtime.h>

// ShiftDisLoss: per-box BEV corner distance loss, weighted global sum / B.
// Inputs: pred_bbox3d [B,N,7] f32, gt_bbox3d [B,N,7] f32, weights [B,N] f32.
// Output: 1 f32 scalar. B=4, N=1e6.
//
// R2 -> R3: the box records (28 B) gave 112 B lane stride on direct loads --
// ~56 cache lines per vmem instruction (issue-bound at 22% HBM). Now each
// block stages a 1024-box tile of pred/gt into LDS via global_load_lds
// width=16 with wave-contiguous addressing (8 lines per instruction), then
// threads read their 4-box groups from LDS.

#define BLOCK 256
#define TILE_BOXES 1024          // per block
#define TILE_F4 1792             // 1024 boxes * 7 floats / 4 per tensor

typedef __attribute__((address_space(1))) const void gas_void;
typedef __attribute__((address_space(3))) void las_void;

__device__ __forceinline__ float fast_rcp(float x) {
    return __builtin_amdgcn_rcpf(x);
}

struct SC { float x0, y0, x1, y1, x2, y2, x3, y3; };

// Algebraic replacement of the reference's corner argsort (see R2): corners
// are c+-u, c+-v; dist^2 keys are |c|^2+|u|^2 +- 2 c.u / 2 c.v, so ordering
// reduces to sign/magnitude selection on t0 = c.u, t1 = c.v; the mid-pair
// x^2 re-sort reduces to sign(cx*qx).
__device__ __forceinline__ SC sorted_corners(float cx, float cy,
                                             float dx, float dy, float h) {
    float s = __sinf(h), c = __cosf(h);
    float hx = 0.5f * dx, hy = 0.5f * dy;
    float ux = hx * c - hy * s, uy = hx * s + hy * c;
    float vx = hx * c + hy * s, vy = hx * s - hy * c;
    float t0 = cx * ux + cy * uy;
    float t1 = cx * vx + cy * vy;
    bool umajor = fabsf(t0) >= fabsf(t1);
    float px = umajor ? ux : vx, py = umajor ? uy : vy;
    float tp = umajor ? t0 : t1;
    float qx = umajor ? vx : ux, qy = umajor ? vy : uy;
    float sp = copysignf(1.0f, tp);
    float sm = copysignf(1.0f, cx * qx);
    SC r;
    r.x0 = cx - sp * px; r.y0 = cy - sp * py;   // nearest
    r.x1 = cx - sm * qx; r.y1 = cy - sm * qy;   // mid (smaller x^2)
    r.x2 = cx + sm * qx; r.y2 = cy + sm * qy;   // mid (larger x^2)
    r.x3 = cx + sp * px; r.y3 = cy + sp * py;   // farthest
    return r;
}

__device__ __forceinline__ float box_loss(float pcx, float pcy, float pdx,
                                          float pdy, float ph,
                                          float gcx, float gcy, float gdx,
                                          float gdy, float gh) {
    SC p = sorted_corners(pcx, pcy, pdx, pdy, ph);
    SC g = sorted_corners(gcx, gcy, gdx, gdy, gh);
    float d1x = g.x1 - g.x0, d1y = g.y1 - g.y0;
    float d2x = g.x2 - g.x0, d2y = g.y2 - g.y0;
    float d3x = g.x3 - g.x0, d3y = g.y3 - g.y0;
    float n1 = d1x * (p.y1 - g.y0) - d1y * (p.x1 - g.x0);
    float n2 = d2x * (p.y2 - g.y0) - d2y * (p.x2 - g.x0);
    float n3 = d3x * (p.y0 - g.y0) - d3y * (p.x0 - g.x0);
    float gx = g.x1 - g.x2, gy = g.y1 - g.y2;
    float diag = gx * gx + gy * gy;
    float sum = n1 * n1 * fast_rcp(d1x * d1x + d1y * d1y)
              + n2 * n2 * fast_rcp(d2x * d2x + d2y * d2y)
              + n3 * n3 * fast_rcp(d3x * d3x + d3y * d3y);
    return sum * fast_rcp(diag);
}

__global__ __launch_bounds__(BLOCK, 2)
void shiftdis_loss_kernel(const float* __restrict__ pred,
                          const float* __restrict__ gt,
                          const float* __restrict__ w,
                          float* __restrict__ out,
                          long long n_boxes, float inv_b) {
    __shared__ float s_pred[TILE_F4 * 4];   // 28 KB
    __shared__ float s_gt[TILE_F4 * 4];     // 28 KB
    __shared__ float wsum[4];

    const int tid = threadIdx.x;
    const int wid = tid >> 6;
    const int lane = tid & 63;

    const long long tileBox = (long long)blockIdx.x * TILE_BOXES;
    const long long f4Base = tileBox * 7 / 4;         // tile start in float4s
    const long long totalF4 = (n_boxes >> 2) * 7;     // full float4s available
    const float4* predF4 = reinterpret_cast<const float4*>(pred);
    const float4* gtF4 = reinterpret_cast<const float4*>(gt);

    // Stage: wave w covers float4s [w*448 + k*64 + lane], k = 0..6.
    // LDS dest is wave-uniform base; HW adds lane*16. Global src is per-lane.
#pragma unroll
    for (int k = 0; k < 7; ++k) {
        long long base = (long long)(wid * 7 + k) * 64;   // f4 offset in tile
        long long gbase = f4Base + base;
        if (gbase + 64 <= totalF4) {                      // uniform guard
            __builtin_amdgcn_global_load_lds(
                (gas_void*)(predF4 + gbase + lane),
                (las_void*)(s_pred + base * 4), 16, 0, 0);
            __builtin_amdgcn_global_load_lds(
                (gas_void*)(gtF4 + gbase + lane),
                (las_void*)(s_gt + base * 4), 16, 0, 0);
        }
    }
    __syncthreads();   // drains vmcnt -> LDS tiles ready

    float acc = 0.0f;
    long long b0 = tileBox + 4LL * tid;

    if (b0 + 4 <= n_boxes) {
        const float4* sp4 = reinterpret_cast<const float4*>(s_pred + tid * 28);
        const float4* sg4 = reinterpret_cast<const float4*>(s_gt + tid * 28);
        float pf[28], gf[28];
#pragma unroll
        for (int i = 0; i < 7; ++i) {
            float4 v = sp4[i];
            pf[4 * i + 0] = v.x; pf[4 * i + 1] = v.y;
            pf[4 * i + 2] = v.z; pf[4 * i + 3] = v.w;
            float4 u = sg4[i];
            gf[4 * i + 0] = u.x; gf[4 * i + 1] = u.y;
            gf[4 * i + 2] = u.z; gf[4 * i + 3] = u.w;
        }
        float4 wv = *reinterpret_cast<const float4*>(w + b0);
        float wa0 = wv.x, wa1 = wv.y, wa2 = wv.z, wa3 = wv.w;

#pragma unroll
        for (int j = 0; j < 4; ++j) {
            float wj = (j == 0) ? wa0 : (j == 1) ? wa1 : (j == 2) ? wa2 : wa3;
            acc += box_loss(pf[7 * j + 0], pf[7 * j + 1], pf[7 * j + 3],
                            pf[7 * j + 4], pf[7 * j + 6],
                            gf[7 * j + 0], gf[7 * j + 1], gf[7 * j + 3],
                            gf[7 * j + 4], gf[7 * j + 6]) * wj;
        }
    } else if (b0 < n_boxes) {
        // ragged tail: read straight from global (rare path)
        for (long long b = b0; b < n_boxes; ++b) {
            const float* p = pred + b * 7;
            const float* q = gt + b * 7;
            acc += box_loss(p[0], p[1], p[3], p[4], p[6],
                            q[0], q[1], q[3], q[4], q[6]) * w[b];
        }
    }

    // wave-64 reduce
#pragma unroll
    for (int off = 32; off > 0; off >>= 1)
        acc += __shfl_down(acc, off, 64);

    if (lane == 0) wsum[wid] = acc;
    __syncthreads();
    if (tid == 0) {
        float bsum = wsum[0] + wsum[1] + wsum[2] + wsum[3];
        atomicAdd(out, bsum * inv_b);
    }
}

extern "C" void kernel_launch(void* const* d_in, const int* in_sizes, int n_in,
                              void* d_out, int out_size, void* d_ws, size_t ws_size,
                              hipStream_t stream) {
    const float* pred = (const float*)d_in[0];
    const float* gt   = (const float*)d_in[1];
    const float* w    = (const float*)d_in[2];
    float* out = (float*)d_out;

    long long n_boxes = (long long)in_sizes[2];   // B*N
    const float inv_b = 0.25f;                    // B = 4

    hipMemsetAsync(d_out, 0, sizeof(float), stream);

    long long grid = (n_boxes + TILE_BOXES - 1) / TILE_BOXES;
    shiftdis_loss_kernel<<<(int)grid, BLOCK, 0, stream>>>(pred, gt, w, out,
                                                          n_boxes, inv_b);
}

// Round 4
// 44.596 us; speedup vs baseline: 1.6833x; 1.6132x over previous
//
#include <hip/hip_runtime.h>

// ShiftDisLoss: per-box BEV corner distance loss, weighted global sum / B.
// Inputs: pred_bbox3d [B,N,7] f32, gt_bbox3d [B,N,7] f32, weights [B,N] f32.
// Output: 1 f32 scalar. B=4, N=1e6.
//
// R3 -> R4: persistent double-buffered pipeline. 512 blocks (2/CU), each
// grid-strides over 512-box tiles. Tile t+1 is staged into the alternate LDS
// buffer via global_load_lds (8 chunks/wave, incl. weights) BEFORE computing
// tile t; raw s_barrier + counted s_waitcnt vmcnt(8) keeps the prefetch in
// flight across barriers (no vmcnt(0) drain in the main loop).

#define BLOCK 256
#define TILE 512                 // boxes per tile
#define NBLOCKS 512              // persistent grid: 2 blocks/CU
#define TILE_F 3584              // TILE*7 floats per tensor tile
#define TILE_F4 896              // TILE*7/4 float4 per tensor tile

typedef __attribute__((address_space(1))) const void gas_void;
typedef __attribute__((address_space(3))) void las_void;

__device__ __forceinline__ float fast_rcp(float x) {
    return __builtin_amdgcn_rcpf(x);
}

struct SC { float x0, y0, x1, y1, x2, y2, x3, y3; };

// Algebraic replacement of the reference's corner argsort (see R2): corners
// are c+-u, c+-v; dist^2 keys are |c|^2+|u|^2 +- 2c.u / 2c.v, so ordering
// reduces to sign/magnitude selection on t0=c.u, t1=c.v; the mid-pair x^2
// re-sort reduces to sign(cx*qx).
__device__ __forceinline__ SC sorted_corners(float cx, float cy,
                                             float dx, float dy, float h) {
    float s = __sinf(h), c = __cosf(h);
    float hx = 0.5f * dx, hy = 0.5f * dy;
    float ux = hx * c - hy * s, uy = hx * s + hy * c;
    float vx = hx * c + hy * s, vy = hx * s - hy * c;
    float t0 = cx * ux + cy * uy;
    float t1 = cx * vx + cy * vy;
    bool umajor = fabsf(t0) >= fabsf(t1);
    float px = umajor ? ux : vx, py = umajor ? uy : vy;
    float tp = umajor ? t0 : t1;
    float qx = umajor ? vx : ux, qy = umajor ? vy : uy;
    float sp = copysignf(1.0f, tp);
    float sm = copysignf(1.0f, cx * qx);
    SC r;
    r.x0 = cx - sp * px; r.y0 = cy - sp * py;   // nearest
    r.x1 = cx - sm * qx; r.y1 = cy - sm * qy;   // mid (smaller x^2)
    r.x2 = cx + sm * qx; r.y2 = cy + sm * qy;   // mid (larger x^2)
    r.x3 = cx + sp * px; r.y3 = cy + sp * py;   // farthest
    return r;
}

__device__ __forceinline__ float box_loss(float pcx, float pcy, float pdx,
                                          float pdy, float ph,
                                          float gcx, float gcy, float gdx,
                                          float gdy, float gh) {
    SC p = sorted_corners(pcx, pcy, pdx, pdy, ph);
    SC g = sorted_corners(gcx, gcy, gdx, gdy, gh);
    float d1x = g.x1 - g.x0, d1y = g.y1 - g.y0;
    float d2x = g.x2 - g.x0, d2y = g.y2 - g.y0;
    float d3x = g.x3 - g.x0, d3y = g.y3 - g.y0;
    float n1 = d1x * (p.y1 - g.y0) - d1y * (p.x1 - g.x0);
    float n2 = d2x * (p.y2 - g.y0) - d2y * (p.x2 - g.x0);
    float n3 = d3x * (p.y0 - g.y0) - d3y * (p.x0 - g.x0);
    float gx = g.x1 - g.x2, gy = g.y1 - g.y2;
    float diag = gx * gx + gy * gy;
    float sum = n1 * n1 * fast_rcp(d1x * d1x + d1y * d1y)
              + n2 * n2 * fast_rcp(d2x * d2x + d2y * d2y)
              + n3 * n3 * fast_rcp(d3x * d3x + d3y * d3y);
    return sum * fast_rcp(diag);
}

__global__ __launch_bounds__(BLOCK, 2)
void shiftdis_loss_kernel(const float* __restrict__ pred,
                          const float* __restrict__ gt,
                          const float* __restrict__ w,
                          float* __restrict__ out,
                          long long n_boxes, float inv_b) {
    __shared__ float sP[2][TILE_F];      // 2 x 14336 B
    __shared__ float sG[2][TILE_F];      // 2 x 14336 B
    __shared__ float sW[2][TILE];        // 2 x 2048 B
    __shared__ float sScratch[256];      // dummy landing (never read)
    __shared__ float wsum[4];

    const int tid = threadIdx.x;
    const int wid = tid >> 6;
    const int lane = tid & 63;

    const float4* predF4 = reinterpret_cast<const float4*>(pred);
    const float4* gtF4 = reinterpret_cast<const float4*>(gt);
    const float4* wF4 = reinterpret_cast<const float4*>(w);

    const long long nfull = n_boxes / TILE;   // full tiles
    const int G = gridDim.x;

    float acc = 0.0f;

    // Stage one tile's pred/gt/weights into LDS buffer `buf`.
    // Per wave: 7 box chunks (1 KB each) + 1 weight/dummy chunk = 8
    // global_load_lds => uniform vmcnt accounting across waves.
    auto STAGE = [&](int buf, long long t) {
        const long long boxF4 = t * (long long)TILE_F4;
#pragma unroll
        for (int k = 0; k < 7; ++k) {
            int c = wid * 7 + k;                 // 0..27 unified chunk id
            int isGt = (c >= 14);
            int cc = isGt ? (c - 14) : c;        // 0..13 within tensor
            const float4* src = (isGt ? gtF4 : predF4) + boxF4 + cc * 64 + lane;
            float* dst = (isGt ? sG[buf] : sP[buf]) + cc * 256;
            __builtin_amdgcn_global_load_lds((gas_void*)src, (las_void*)dst,
                                             16, 0, 0);
        }
        {
            const long long wb = t * (long long)(TILE / 4);
            const float4* src = wF4 + wb + (wid & 1) * 64 + lane;
            float* dst = (wid < 2) ? (sW[buf] + wid * 256) : sScratch;
            __builtin_amdgcn_global_load_lds((gas_void*)src, (las_void*)dst,
                                             16, 0, 0);
        }
    };

    if ((long long)blockIdx.x < nfull) {
        STAGE(0, (long long)blockIdx.x);
        int cur = 0;
        for (long long t = blockIdx.x; t < nfull; t += G) {
            long long tn = t + G;
            if (tn < nfull) {
                STAGE(cur ^ 1, tn);
                // own 8 cur-tile loads complete; 8 next-tile loads in flight
                asm volatile("s_waitcnt vmcnt(8)" ::: "memory");
            } else {
                asm volatile("s_waitcnt vmcnt(0)" ::: "memory");
            }
            __builtin_amdgcn_sched_barrier(0);
            __builtin_amdgcn_s_barrier();      // cur tile visible to all waves
            __builtin_amdgcn_sched_barrier(0);

#pragma unroll
            for (int j = 0; j < 2; ++j) {
                int b = tid + j * 256;           // 0..511 within tile
                const float* P = sP[cur] + b * 7;
                const float* Q = sG[cur] + b * 7;
                float wt = sW[cur][b];
                acc += box_loss(P[0], P[1], P[3], P[4], P[6],
                                Q[0], Q[1], Q[3], Q[4], Q[6]) * wt;
            }

            __builtin_amdgcn_sched_barrier(0);
            __builtin_amdgcn_s_barrier();      // all done reading cur buffer
            __builtin_amdgcn_sched_barrier(0);
            cur ^= 1;
        }
    }

    // ragged tail (n % TILE boxes), block 0 only, direct from global
    if (blockIdx.x == 0) {
        for (long long b = nfull * TILE + tid; b < n_boxes; b += BLOCK) {
            const float* p = pred + b * 7;
            const float* q = gt + b * 7;
            acc += box_loss(p[0], p[1], p[3], p[4], p[6],
                            q[0], q[1], q[3], q[4], q[6]) * w[b];
        }
    }

    // wave-64 reduce
#pragma unroll
    for (int off = 32; off > 0; off >>= 1)
        acc += __shfl_down(acc, off, 64);

    if (lane == 0) wsum[wid] = acc;
    __syncthreads();
    if (tid == 0) {
        float bsum = wsum[0] + wsum[1] + wsum[2] + wsum[3];
        atomicAdd(out, bsum * inv_b);
    }
}

extern "C" void kernel_launch(void* const* d_in, const int* in_sizes, int n_in,
                              void* d_out, int out_size, void* d_ws, size_t ws_size,
                              hipStream_t stream) {
    const float* pred = (const float*)d_in[0];
    const float* gt   = (const float*)d_in[1];
    const float* w    = (const float*)d_in[2];
    float* out = (float*)d_out;

    long long n_boxes = (long long)in_sizes[2];   // B*N
    const float inv_b = 0.25f;                    // B = 4

    hipMemsetAsync(d_out, 0, sizeof(float), stream);

    shiftdis_loss_kernel<<<NBLOCKS, BLOCK, 0, stream>>>(pred, gt, w, out,
                                                        n_boxes, inv_b);
}